// Round 1
// 245.876 us; speedup vs baseline: 1.0130x; 1.0130x over previous
//
#include <hip/hip_runtime.h>

#define NL 64
#define SQ 512
#define BATCH 1024
#define TMID 256   // forward owns t=0..255, backward owns t=511..256

typedef __fp16 hf2 __attribute__((ext_vector_type(2)));

#define EXP2F(x)  __builtin_amdgcn_exp2f(x)   // 2^x (v_exp_f32)
#define LOG2F(x)  __builtin_amdgcn_logf(x)    // log2 (v_log_f32)

__device__ __forceinline__ float lane0_bcast(float v) {
    return __uint_as_float(__builtin_amdgcn_readfirstlane(__float_as_uint(v)));
}
__device__ __forceinline__ hf2 bc2(int pki, int lane) {
    int v = __builtin_amdgcn_readlane(pki, lane);
    return __builtin_bit_cast(hf2, v);
}

// Round-7: same fwd/bwd split + dpp-pack + f16 dot2 matvec as round 6.
// Latency fixes for the measured ~33% stall (VALUBusy 67%, 0 bank conflicts,
// HBM 8% of peak, ~515 cyc/wave-step vs ~170 issue cyc):
//  (1) masks: 16B-aligned int4 scalar loads, prefetched one 8-step group
//      ahead (was: loaded immediately before use -> exposed SMEM latency
//      once per 4 steps).
//  (2) emissions: 8-deep register double-buffer (one full group ahead,
//      >1300 issue-cycles of cover vs ~600 before; covers HBM ~900 cyc).
//  (3) renorm by exponent bits: scale = 2^(124-eb) is EXACT, replaces
//      v_rcp_f32 + v_log_f32 (quarter-rate trans, on the serial chain) with
//      readfirstlane + 3 SALU ops; log2-offset accumulates as an integer.
//  (4) dot2 chain widened to 8 accumulators (depth 8 -> 4).
// f16 window unchanged: lane0 scaled into [0.125,0.25), spread bounded by
// per-step emission spread (~e^9) -> max ~2.5e3 << 65504.
__global__ __launch_bounds__(64, 2) void crf_scan(
    const float* __restrict__ emissions,   // [B, S, L]
    const int*   __restrict__ mask,        // [B, S]
    const float* __restrict__ trans,       // [L, L]
    const float* __restrict__ start_t,     // [L]
    const float* __restrict__ end_t,       // [L]
    float* __restrict__ ws_p,              // [2B][64]
    float* __restrict__ ws_c)              // [2B]  (log2-domain offsets)
{
    const int  blk = blockIdx.x;
    const bool fwd = blk < BATCH;
    const int  b   = fwd ? blk : blk - BATCH;
    const int  j   = threadIdx.x;
    const float LOG2E = 1.44269504088896340736f;

    const float* em = emissions + (size_t)b * SQ * NL;
    const int*   mk = mask + (size_t)b * SQ;

    // ET as 32 packed f16 pairs: fwd lane j = column ET[:,j]; bwd lane i = row.
    hf2 et2[NL / 2];
#pragma unroll
    for (int k = 0; k < NL / 2; ++k) {
        float e0, e1;
        if (fwd) { e0 = __expf(trans[(2*k + 0) * NL + j]);
                   e1 = __expf(trans[(2*k + 1) * NL + j]); }
        else     { e0 = __expf(trans[j * NL + (2*k + 0)]);
                   e1 = __expf(trans[j * NL + (2*k + 1)]); }
        et2[k] = __builtin_amdgcn_cvt_pkrtz(e0, e1);
    }

    // sum_i x_i * et[i] via packed-f16 dot2, broadcast from even lanes.
    auto matvec = [&](float xb) -> float {
        int nb = __builtin_amdgcn_update_dpp(0, __float_as_int(xb),
                                             0xB1, 0xF, 0xF, true); // quad_perm(1,0,3,2)
        hf2 pk = __builtin_amdgcn_cvt_pkrtz(xb, __int_as_float(nb));
        int pki = __builtin_bit_cast(int, pk);
        float a0 = 0.f, a1 = 0.f, a2 = 0.f, a3 = 0.f;
        float a4 = 0.f, a5 = 0.f, a6 = 0.f, a7 = 0.f;
#pragma unroll
        for (int k = 0; k < 32; k += 8) {
            a0 = __builtin_amdgcn_fdot2(bc2(pki, 2*(k+0)), et2[k+0], a0, false);
            a1 = __builtin_amdgcn_fdot2(bc2(pki, 2*(k+1)), et2[k+1], a1, false);
            a2 = __builtin_amdgcn_fdot2(bc2(pki, 2*(k+2)), et2[k+2], a2, false);
            a3 = __builtin_amdgcn_fdot2(bc2(pki, 2*(k+3)), et2[k+3], a3, false);
            a4 = __builtin_amdgcn_fdot2(bc2(pki, 2*(k+4)), et2[k+4], a4, false);
            a5 = __builtin_amdgcn_fdot2(bc2(pki, 2*(k+5)), et2[k+5], a5, false);
            a6 = __builtin_amdgcn_fdot2(bc2(pki, 2*(k+6)), et2[k+6], a6, false);
            a7 = __builtin_amdgcn_fdot2(bc2(pki, 2*(k+7)), et2[k+7], a7, false);
        }
        return ((a0 + a1) + (a2 + a3)) + ((a4 + a5) + (a6 + a7));
    };

    float p, base;       // state (f32, renormed each step) + f32 log2 base
    int   esum = 0;      // integer log2-domain renorm accumulator

    if (fwd) {
        // ---- prefetch: peel t=1..3 + groups 0 (regs) with masks ----
        float pe1 = em[1*NL + j], pe2 = em[2*NL + j], pe3 = em[3*NL + j];
        int   pm1 = mk[1], pm2 = mk[2], pm3 = mk[3];
        float r0 = em[ 4*NL + j], r1 = em[ 5*NL + j];
        float r2 = em[ 6*NL + j], r3 = em[ 7*NL + j];
        float r4 = em[ 8*NL + j], r5 = em[ 9*NL + j];
        float r6 = em[10*NL + j], r7 = em[11*NL + j];
        int4 M0 = *reinterpret_cast<const int4*>(mk + 4);   // t=4..7
        int4 M1 = *reinterpret_cast<const int4*>(mk + 8);   // t=8..11

        const float s0f = start_t[j] + em[j];               // t = 0
        const float C   = lane0_bcast(s0f);
        p = EXP2F((s0f - C) * LOG2E);  base = C * LOG2E;

        auto step = [&](float r, int m) {
            const float ex = EXP2F(r * LOG2E);              // e^emit
            const unsigned u = __builtin_amdgcn_readfirstlane(__float_as_uint(p));
            const int eb = (int)((u >> 23) & 0xffu);
            const float scale = __uint_as_float((unsigned)(251 - eb) << 23); // 2^(124-eb)
            const float mv = matvec(p * scale);
            if (m) { p = ex * mv; esum += eb - 124; }
        };

        step(pe1, pm1); step(pe2, pm2); step(pe3, pm3);     // t = 1..3

        for (int G = 0; G < 31; ++G) {                      // t = 4+8G .. 11+8G
            const int t0 = 4 + 8 * G;
            // prefetch group G+1 (indices clamp only on the last iteration)
            const int t8 = t0 + 8;
            const int tA = (t0+12 > 255) ? 255 : t0+12;
            const int tB = (t0+13 > 255) ? 255 : t0+13;
            const int tC = (t0+14 > 255) ? 255 : t0+14;
            const int tD = (t0+15 > 255) ? 255 : t0+15;
            float n0 = em[(t8+0)*NL + j], n1 = em[(t8+1)*NL + j];
            float n2 = em[(t8+2)*NL + j], n3 = em[(t8+3)*NL + j];
            float n4 = em[tA*NL + j],     n5 = em[tB*NL + j];
            float n6 = em[tC*NL + j],     n7 = em[tD*NL + j];
            int4 nM0 = *reinterpret_cast<const int4*>(mk + t8);
            const int tm1 = (t0+12 > 252) ? 252 : t0+12;    // keep 16B-aligned, in-bounds
            int4 nM1 = *reinterpret_cast<const int4*>(mk + tm1);

            step(r0, M0.x); step(r1, M0.y); step(r2, M0.z); step(r3, M0.w);
            step(r4, M1.x); step(r5, M1.y); step(r6, M1.z); step(r7, M1.w);

            r0=n0; r1=n1; r2=n2; r3=n3; r4=n4; r5=n5; r6=n6; r7=n7;
            M0=nM0; M1=nM1;
        }
        // tail t=252..255 (r0..r3 = em[252..255], M0 = mk[252..255])
        step(r0, M0.x); step(r1, M0.y); step(r2, M0.z); step(r3, M0.w);
    } else {
        float r0 = em[511*NL + j], r1 = em[510*NL + j];
        float r2 = em[509*NL + j], r3 = em[508*NL + j];
        float r4 = em[507*NL + j], r5 = em[506*NL + j];
        float r6 = em[505*NL + j], r7 = em[504*NL + j];
        int4 Ma = *reinterpret_cast<const int4*>(mk + 508); // {508..511}
        int4 Mb = *reinterpret_cast<const int4*>(mk + 504); // {504..507}

        p = __expf(end_t[j]);  base = 0.f;                  // q_511

        auto step = [&](float r, int m) {
            const float ex = EXP2F(r * LOG2E);
            const float sc = ex * p;                        // scale BEFORE matvec
            const unsigned u = __builtin_amdgcn_readfirstlane(__float_as_uint(sc));
            const int eb = (int)((u >> 23) & 0xffu);
            const float scale = __uint_as_float((unsigned)(251 - eb) << 23); // 2^(124-eb)
            const float mv = matvec(sc * scale);
            if (m) { p = mv; esum += eb - 124; }
        };

        for (int G = 0; G < 32; ++G) {                      // t = 511-8G .. 504-8G
            const int t0 = 511 - 8 * G;
            const int tb = t0 - 8;
            // prefetch group G+1 (pure clamp-dups on the last iteration, unused)
            const int te0 = (tb-0 < 256) ? 256 : tb-0;
            const int te1 = (tb-1 < 256) ? 256 : tb-1;
            const int te2 = (tb-2 < 256) ? 256 : tb-2;
            const int te3 = (tb-3 < 256) ? 256 : tb-3;
            const int te4 = (tb-4 < 256) ? 256 : tb-4;
            const int te5 = (tb-5 < 256) ? 256 : tb-5;
            const int te6 = (tb-6 < 256) ? 256 : tb-6;
            const int te7 = (tb-7 < 256) ? 256 : tb-7;
            float n0 = em[te0*NL + j], n1 = em[te1*NL + j];
            float n2 = em[te2*NL + j], n3 = em[te3*NL + j];
            float n4 = em[te4*NL + j], n5 = em[te5*NL + j];
            float n6 = em[te6*NL + j], n7 = em[te7*NL + j];
            const int ta  = (tb-3 < 256) ? 256 : tb-3;      // 16B-aligned
            const int tbb = (tb-7 < 256) ? 256 : tb-7;      // 16B-aligned
            int4 nMa = *reinterpret_cast<const int4*>(mk + ta);
            int4 nMb = *reinterpret_cast<const int4*>(mk + tbb);

            step(r0, Ma.w); step(r1, Ma.z); step(r2, Ma.y); step(r3, Ma.x);
            step(r4, Mb.w); step(r5, Mb.z); step(r6, Mb.y); step(r7, Mb.x);

            r0=n0; r1=n1; r2=n2; r3=n3; r4=n4; r5=n5; r6=n6; r7=n7;
            Ma=nMa; Mb=nMb;
        }
    }

    ws_p[(size_t)blk * NL + j] = p;
    if (j == 0) ws_c[blk] = base + (float)esum;
}

// out[b] = ln2 * ( c2f + c2b + log2( sum_j pf[j] * pb[j] ) )
__global__ __launch_bounds__(64) void crf_combine(
    const float* __restrict__ ws_p, const float* __restrict__ ws_c,
    float* __restrict__ out)
{
    const int b = blockIdx.x;
    const int j = threadIdx.x;
    float v = ws_p[(size_t)b * NL + j] * ws_p[(size_t)(b + BATCH) * NL + j];
#pragma unroll
    for (int off = 32; off; off >>= 1) v += __shfl_xor(v, off);
    if (j == 0)
        out[b] = 0.69314718055994530942f *
                 (ws_c[b] + ws_c[b + BATCH] + LOG2F(v));
}

extern "C" void kernel_launch(void* const* d_in, const int* in_sizes, int n_in,
                              void* d_out, int out_size, void* d_ws, size_t ws_size,
                              hipStream_t stream) {
    const float* emissions = (const float*)d_in[0];
    const int*   mask      = (const int*)d_in[1];
    const float* trans     = (const float*)d_in[2];
    const float* start_t   = (const float*)d_in[3];
    const float* end_t     = (const float*)d_in[4];
    float* out = (float*)d_out;

    float* ws_p = (float*)d_ws;                    // 2*1024*64 floats
    float* ws_c = ws_p + 2 * BATCH * NL;           // 2*1024 floats

    crf_scan<<<2 * BATCH, NL, 0, stream>>>(emissions, mask, trans,
                                           start_t, end_t, ws_p, ws_c);
    crf_combine<<<BATCH, NL, 0, stream>>>(ws_p, ws_c, out);
}